// Round 18
// baseline (129.398 us; speedup 1.0000x reference)
//
#include <hip/hip_runtime.h>

// FANS: B=131072 rows x 16 states, MLP 12->64->64->1 with tanh, fp32 in/out.
// R18 = R17 (74.1us, WIN, prediction matched) + cross-chunk software pipeline.
// R17 accounting: ~10k cyc/chunk/SIMD dependency stall; ~500 serial cyc/chunk
// is the phase-1 prologue (gather ~300 + pack + ds round-trip) with all 4
// waves in phase. zpl rows are PER-WAVE-PRIVATE (wave w writes/reads only
// rows [64w,64w+64)), so the chunk loop pipelines with no barrier:
//   prologue: gather+stage chunk 0
//   iter ch:  issue global gather for ch+1 into regs (latency spans the whole
//             chunk's compute) -> run both 32-row tiles -> pack+write zpl for
//             ch+1 (same-wave DS ordering makes the WAR safe).
// Cost ~16 live VGPRs (arch ~80, unified ~115 < 128 cap; launch_bounds(256,4)).
// Kept from R17: 32x32x16 MFMA both layers (layouts verified by absmax),
// pk-f16 tanh, a0 8 regs / a1 32 regs, v_dot2 layer-3, Hd stride 36, CHUNK=8.

#define N_STATES 16
#define CHUNK    8

typedef _Float16 f16x8  __attribute__((ext_vector_type(8)));
typedef float    f32x16 __attribute__((ext_vector_type(16)));
typedef __fp16   h2     __attribute__((ext_vector_type(2)));

__device__ __forceinline__ h2 pack2(float a, float b) {
    return __builtin_amdgcn_cvt_pkrtz(a, b);
}
__device__ __forceinline__ unsigned int h2_bits(h2 v) {
    union { h2 h; unsigned int u; } x; x.h = v; return x.u;
}
__device__ __forceinline__ f16x8 u4_to_h8(uint4 v) {
    union { uint4 u; f16x8 h; } x; x.u = v; return x.h;
}

// Packed-f16 tanh: clamp(+-1.25) then odd Chebyshev poly; v_pk_* full-rate.
__device__ __forceinline__ h2 tanh_pk(h2 x) {
    const h2 hi = {(__fp16)1.25f, (__fp16)1.25f};
    const h2 lo = {(__fp16)-1.25f, (__fp16)-1.25f};
    x = __builtin_elementwise_min(__builtin_elementwise_max(x, lo), hi);
    h2 s = x * x;
    const h2 c4 = {(__fp16)0.00598591f, (__fp16)0.00598591f};
    const h2 c3 = {(__fp16)-0.03807894f, (__fp16)-0.03807894f};
    const h2 c2 = {(__fp16)0.12576901f, (__fp16)0.12576901f};
    const h2 c1 = {(__fp16)-0.33203310f, (__fp16)-0.33203310f};
    const h2 c0 = {(__fp16)0.99998110f, (__fp16)0.99998110f};
    h2 p = s * c4 + c3;
    p = s * p + c2;
    p = s * p + c1;
    p = s * p + c0;
    return x * p;
}

__global__ __launch_bounds__(256, 4) void fans_mfma_kernel(
    const float* __restrict__ x_f, const float* __restrict__ x_b,
    const float* __restrict__ u,   const float* __restrict__ W0,
    const float* __restrict__ W1,  const float* __restrict__ W2,
    float* __restrict__ out)
{
    __shared__ __align__(16) uint4 zplA[256];              // 4 KB: z dwords 0..3
    __shared__ __align__(16) uint2 zplB[256];              // 2 KB: u pair
    __shared__ __align__(16) unsigned int Hd[4][32][36];   // 18 KB: [wave][row][pair]

    const int s   = blockIdx.y;
    const int tid = threadIdx.x;
    const int b0  = blockIdx.x * (256 * CHUNK);

    const int lid = tid & 63;
    const int w   = tid >> 6;     // wave id; wave w owns local rows [64w,64w+64)
    const int n   = lid & 31;     // batch row within 32-tile / feat row for A
    const int h   = lid >> 5;     // K-half (k = 8h+j)

    // ---- layer-1 A-frags in regs (2 x f16x8 = 8 regs) ----
    f16x8 a0[2];
    {
        const float* w0s = W0 + s * 768;
        #pragma unroll
        for (int Mh = 0; Mh < 2; ++Mh) {
            const float* base = w0s + (32 * Mh + n) * 12;
            f16x8 v;
            if (h == 0) {
                const float4 v0 = *(const float4*)(base + 0);
                const float4 v1 = *(const float4*)(base + 4);
                v = (f16x8){(_Float16)v0.x, (_Float16)v0.y, (_Float16)v0.z, (_Float16)v0.w,
                            (_Float16)v1.x, (_Float16)v1.y, (_Float16)v1.z, (_Float16)v1.w};
            } else {
                const float4 v0 = *(const float4*)(base + 8);   // k=8..11
                v = (f16x8){(_Float16)v0.x, (_Float16)v0.y, (_Float16)v0.z, (_Float16)v0.w,
                            (_Float16)0.f, (_Float16)0.f, (_Float16)0.f, (_Float16)0.f};
            }
            a0[Mh] = v;
        }
    }
    // ---- layer-2 A-frags in regs (8 x f16x8 = 32 regs) ----
    f16x8 a1[2][4];
    {
        const float* w1s = W1 + s * 4096;
        #pragma unroll
        for (int Mh = 0; Mh < 2; ++Mh) {
            #pragma unroll
            for (int kc = 0; kc < 4; ++kc) {
                const float4* p = (const float4*)(w1s + (32 * Mh + n) * 64 + 16 * kc + 8 * h);
                const float4 v0 = p[0], v1 = p[1];
                a1[Mh][kc] = (f16x8){(_Float16)v0.x, (_Float16)v0.y, (_Float16)v0.z, (_Float16)v0.w,
                                     (_Float16)v1.x, (_Float16)v1.y, (_Float16)v1.z, (_Float16)v1.w};
            }
        }
    }
    // ---- W2 packed pairs: this lane's feats = 32Mh + 8a + 2b + 4h ----
    h2 w2p[16];
    {
        const float* w2s = W2 + s * 64;
        #pragma unroll
        for (int Mh = 0; Mh < 2; ++Mh)
            #pragma unroll
            for (int k = 0; k < 8; ++k) {
                const int f = 32 * Mh + 8 * (k >> 1) + 2 * (k & 1) + 4 * h;
                w2p[8 * Mh + k] = pack2(w2s[f], w2s[f + 1]);
            }
    }

    const int wrap = (s > 8) ? (s - 8) : 0;   // IDX[s] = {0..wrap-1}++{s..15}

    // ---- prologue: gather + stage chunk 0 ----
    {
        const int row = b0 + tid;
        float zs[8];
        #pragma unroll
        for (int j = 0; j < 8; ++j) {
            const int idx = (j < wrap) ? j : (s + j - wrap);  // uniform
            zs[j] = (idx < 8) ? x_f[row * 8 + idx] : x_b[row * 8 + (idx - 8)];
        }
        const float4 uv = *(const float4*)(u + row * 4);
        zplA[tid] = make_uint4(h2_bits(pack2(zs[0], zs[1])), h2_bits(pack2(zs[2], zs[3])),
                               h2_bits(pack2(zs[4], zs[5])), h2_bits(pack2(zs[6], zs[7])));
        zplB[tid] = make_uint2(h2_bits(pack2(uv.x, uv.y)), h2_bits(pack2(uv.z, uv.w)));
    }

    #pragma unroll 1
    for (int ch = 0; ch < CHUNK; ++ch) {
        const int rbase = b0 + ch * 256;

        // ---- issue next chunk's gather NOW; latency spans this chunk ----
        float zn[8];
        float4 un;
        if (ch + 1 < CHUNK) {
            const int row = rbase + 256 + tid;
            #pragma unroll
            for (int j = 0; j < 8; ++j) {
                const int idx = (j < wrap) ? j : (s + j - wrap);  // uniform
                zn[j] = (idx < 8) ? x_f[row * 8 + idx] : x_b[row * 8 + (idx - 8)];
            }
            un = *(const float4*)(u + row * 4);
        }

        // ---- phase 2: two 32-row tiles (reads own wave's zpl rows) ----
        #pragma unroll
        for (int m = 0; m < 2; ++m) {
            const int rowb = 64 * w + 32 * m;

            // z B-frag: B[k=8h+j][n]: h=0 -> z dwords 0..3; h=1 -> u pair + 0
            f16x8 zf;
            if (h == 0) {
                zf = u4_to_h8(zplA[rowb + n]);
            } else {
                const uint2 b = zplB[rowb + n];
                zf = u4_to_h8(make_uint4(b.x, b.y, 0u, 0u));
            }

            // layer 1: 2 MFMAs (M-halves)
            const f32x16 z16 = {0.f,0.f,0.f,0.f,0.f,0.f,0.f,0.f,
                                0.f,0.f,0.f,0.f,0.f,0.f,0.f,0.f};
            f32x16 c1a = __builtin_amdgcn_mfma_f32_32x32x16_f16(a0[0], zf, z16, 0, 0, 0);
            f32x16 c1b = __builtin_amdgcn_mfma_f32_32x32x16_f16(a0[1], zf, z16, 0, 0, 0);

            // tanh -> pair-pack -> Hd[w][n][pair]: pairs p=16Mh+4a+2h, +1
            #pragma unroll
            for (int a = 0; a < 4; ++a) {
                const int r = 4 * a;
                *(uint2*)&Hd[w][n][16 * 0 + 4 * a + 2 * h] =
                    make_uint2(h2_bits(tanh_pk(pack2(c1a[r], c1a[r + 1]))),
                               h2_bits(tanh_pk(pack2(c1a[r + 2], c1a[r + 3]))));
                *(uint2*)&Hd[w][n][16 * 1 + 4 * a + 2 * h] =
                    make_uint2(h2_bits(tanh_pk(pack2(c1b[r], c1b[r + 1]))),
                               h2_bits(tanh_pk(pack2(c1b[r + 2], c1b[r + 3]))));
            }

            // layer 2: B-frag kc: features 16kc+8h+j = pairs 8kc+4h+[0..4) (b128)
            f32x16 c2a = z16, c2b = z16;
            #pragma unroll
            for (int kc = 0; kc < 4; ++kc) {
                const f16x8 hb = u4_to_h8(*(const uint4*)&Hd[w][n][8 * kc + 4 * h]);
                c2a = __builtin_amdgcn_mfma_f32_32x32x16_f16(a1[0][kc], hb, c2a, 0, 0, 0);
                c2b = __builtin_amdgcn_mfma_f32_32x32x16_f16(a1[1][kc], hb, c2b, 0, 0, 0);
            }

            // layer 3: packed tanh + v_dot2; this lane covers 32 feats of row n
            float ar0 = 0.f, ar1 = 0.f;
            #pragma unroll
            for (int a = 0; a < 4; ++a) {
                const int r = 4 * a;
                ar0 = __builtin_amdgcn_fdot2(tanh_pk(pack2(c2a[r], c2a[r + 1])), w2p[2 * a + 0], ar0, false);
                ar0 = __builtin_amdgcn_fdot2(tanh_pk(pack2(c2a[r + 2], c2a[r + 3])), w2p[2 * a + 1], ar0, false);
                ar1 = __builtin_amdgcn_fdot2(tanh_pk(pack2(c2b[r], c2b[r + 1])), w2p[8 + 2 * a + 0], ar1, false);
                ar1 = __builtin_amdgcn_fdot2(tanh_pk(pack2(c2b[r + 2], c2b[r + 3])), w2p[8 + 2 * a + 1], ar1, false);
            }
            float acc = ar0 + ar1;
            acc += __shfl_xor(acc, 32);       // combine h=0/h=1 halves

            if (lid < 32)
                out[(rbase + rowb + n) * N_STATES + s] = acc;
        }

        // ---- stage next chunk into zpl (after this chunk's zf reads; ----
        // ---- same-wave DS ordering makes the per-wave WAR safe)       ----
        if (ch + 1 < CHUNK) {
            zplA[tid] = make_uint4(h2_bits(pack2(zn[0], zn[1])), h2_bits(pack2(zn[2], zn[3])),
                                   h2_bits(pack2(zn[4], zn[5])), h2_bits(pack2(zn[6], zn[7])));
            zplB[tid] = make_uint2(h2_bits(pack2(un.x, un.y)), h2_bits(pack2(un.z, un.w)));
        }
    }
}

extern "C" void kernel_launch(void* const* d_in, const int* in_sizes, int n_in,
                              void* d_out, int out_size, void* d_ws, size_t ws_size,
                              hipStream_t stream) {
    const float* x_f = (const float*)d_in[0];
    const float* x_b = (const float*)d_in[1];
    const float* u   = (const float*)d_in[2];
    const float* W0  = (const float*)d_in[3];
    const float* W1  = (const float*)d_in[4];
    const float* W2  = (const float*)d_in[5];
    float* out = (float*)d_out;

    const int nb = in_sizes[0] / 8;                 // 131072 = 64 * 2048
    dim3 grid(nb / (256 * CHUNK), N_STATES);        // (64, 16) = 1024 blocks
    fans_mfma_kernel<<<grid, 256, 0, stream>>>(x_f, x_b, u, W0, W1, W2, out);
}